// Round 12
// baseline (48.539 us; speedup 1.0000x reference)
//
#include <hip/hip_runtime.h>

#define N_FFT    1024
#define HOP      256
#define BATCH    16
#define T_LEN    262144
#define PAD      512
#define N_FRAMES 1025
#define N_FREQ   513
#define FPB      16
#define NTILES   65         // ceil(1025/16)

// output staging tile index: stride 17 + skew; extract writes conflict-free
// (273 mod 32 = 17, coprime with 32), flush reads <=3-way.
#define OTI(f) ((f) * 17 + ((f) >> 4))
#define OT_SZ  (OTI(512) + 17)

__device__ constexpr int   R4_[16] = {0,8,4,12,2,10,6,14,1,9,5,13,3,11,7,15}; // rev4
__device__ constexpr float CA_[16] = {   // cos(2*pi*k/16)
     1.0f,           0.92387953251f,  0.70710678119f,  0.38268343236f,
     0.0f,          -0.38268343236f, -0.70710678119f, -0.92387953251f,
    -1.0f,          -0.92387953251f, -0.70710678119f, -0.38268343236f,
     0.0f,           0.38268343236f,  0.70710678119f,  0.92387953251f};
__device__ constexpr float SA_[16] = {   // sin(2*pi*k/16)
     0.0f,           0.38268343236f,  0.70710678119f,  0.92387953251f,
     1.0f,           0.92387953251f,  0.70710678119f,  0.38268343236f,
     0.0f,          -0.38268343236f, -0.70710678119f, -0.92387953251f,
    -1.0f,          -0.92387953251f, -0.70710678119f, -0.38268343236f};

// Block = (batch, 16-frame tile), 256 threads = 4 waves.
// Each wave processes TWO frame-pairs (4 frames) with interleaved register
// chains for ILP. Symmetric sequence s[n]=0.5*w[n]*(x[n]+x[-n]) built directly
// at load (even-part trick without shuffles); S=FFT(s): ReS=ReA, ImS=ReB.
// 1024-pt DIF FFT fully in registers: stages 512..64 reg-local, 32..1 shfl_xor.
// LDS = output tile only; ONE barrier per block.
__global__ __launch_bounds__(256)
void stft_kernel(const float* __restrict__ x, float* __restrict__ out,
                 unsigned long long cap)
{
    __shared__ float ot[OT_SZ];

    const int tid  = threadIdx.x;
    const int wv   = tid >> 6;
    const int lane = tid & 63;
    const int tile = blockIdx.x % NTILES;
    const int b    = blockIdx.x / NTILES;
    const int t0   = tile * FPB;

    const float TWO_PI = 6.283185307179586f;

    // per-lane twiddle bases: wL = exp(-2pi*i*lane/1024), powers by squaring
    float sLv, cLv;
    sincosf(TWO_PI * (float)lane * (1.0f / 1024.0f), &sLv, &cLv);
    const float w1r = cLv, w1i = -sLv;
    const float w2r = w1r*w1r - w1i*w1i,      w2i = 2.0f*w1r*w1i;
    const float w4r = w2r*w2r - w2i*w2i,      w4i = 2.0f*w2r*w2i;
    const float w8r = w4r*w4r - w4i*w4i,      w8i = 2.0f*w4r*w4i;
    const float w16r = w8r*w8r - w8i*w8i,     w16i = 2.0f*w8r*w8i;
    const float w32r = w16r*w16r - w16i*w16i, w32i = 2.0f*w16r*w16i;
    const float w64r  = CA_[lane & 15],        w64i  = -SA_[lane & 15];
    const float w128r = CA_[(lane & 7) << 1],  w128i = -SA_[(lane & 7) << 1];
    const float w256r = CA_[(lane & 3) << 2],  w256i = -SA_[(lane & 3) << 2];

    const float* xb = x + (size_t)b * T_LEN;
    const int base0 = (t0 + 4 * wv) * HOP - PAD;     // pair 0: frames tA0, tA0+1
    const int base1 = base0 + 2 * HOP;               // pair 1: frames tA0+2, tA0+3
    const bool safe = (base0 >= 0) && (base1 + HOP + 1023 < T_LEN);

    float sr[2][16], si[2][16];

    // ---- load: s[n] = 0.5*w[n]*(x[p+n] + x[p+m]), m=(1024-n)&1023 (w[m]=w[n])
    if (safe) {
        #pragma unroll
        for (int r = 0; r < 16; ++r) {
            const int n = (r << 6) | lane;
            const int m = (1024 - n) & 1023;
            const float wh = 0.25f - 0.25f * (CA_[r] * cLv - SA_[r] * sLv);
            sr[0][r] = wh * (xb[base0 + n]       + xb[base0 + m]);
            si[0][r] = wh * (xb[base0 + HOP + n] + xb[base0 + HOP + m]);
            sr[1][r] = wh * (xb[base1 + n]       + xb[base1 + m]);
            si[1][r] = wh * (xb[base1 + HOP + n] + xb[base1 + HOP + m]);
        }
    } else {
        auto rfl = [](int p) {
            p = (p < 0) ? -p : p;
            return (p >= T_LEN) ? (2 * (T_LEN - 1) - p) : p;
        };
        #pragma unroll
        for (int r = 0; r < 16; ++r) {
            const int n = (r << 6) | lane;
            const int m = (1024 - n) & 1023;
            const float wh = 0.25f - 0.25f * (CA_[r] * cLv - SA_[r] * sLv);
            sr[0][r] = wh * (xb[rfl(base0 + n)]       + xb[rfl(base0 + m)]);
            si[0][r] = wh * (xb[rfl(base0 + HOP + n)] + xb[rfl(base0 + HOP + m)]);
            sr[1][r] = wh * (xb[rfl(base1 + n)]       + xb[rfl(base1 + m)]);
            si[1][r] = wh * (xb[rfl(base1 + HOP + n)] + xb[rfl(base1 + HOP + m)]);
        }
    }

    // ---- DIF stage h=512: pairs (r, r+8), tw = wL * C16^r ----
    #pragma unroll
    for (int pp = 0; pp < 2; ++pp)
    #pragma unroll
    for (int r = 0; r < 8; ++r) {
        const int v = r + 8;
        float dr = sr[pp][r] - sr[pp][v], di = si[pp][r] - si[pp][v];
        sr[pp][r] += sr[pp][v];  si[pp][r] += si[pp][v];
        float er = dr * w1r - di * w1i;
        float ei = dr * w1i + di * w1r;
        sr[pp][v] = er * CA_[r] + ei * SA_[r];
        si[pp][v] = ei * CA_[r] - er * SA_[r];
    }
    // ---- stage h=256: pairs (8g+k, +4), tw = wL2 * C8^k ----
    #pragma unroll
    for (int pp = 0; pp < 2; ++pp)
    #pragma unroll
    for (int g = 0; g < 2; ++g)
    #pragma unroll
    for (int k = 0; k < 4; ++k) {
        const int u = (g << 3) + k, v = u + 4;
        float dr = sr[pp][u] - sr[pp][v], di = si[pp][u] - si[pp][v];
        sr[pp][u] += sr[pp][v];  si[pp][u] += si[pp][v];
        float er = dr * w2r - di * w2i;
        float ei = dr * w2i + di * w2r;
        sr[pp][v] = er * CA_[2 * k] + ei * SA_[2 * k];
        si[pp][v] = ei * CA_[2 * k] - er * SA_[2 * k];
    }
    // ---- stage h=128: pairs (4g+k, +2), tw = wL4 * C4^k ----
    #pragma unroll
    for (int pp = 0; pp < 2; ++pp)
    #pragma unroll
    for (int g = 0; g < 4; ++g)
    #pragma unroll
    for (int k = 0; k < 2; ++k) {
        const int u = (g << 2) + k, v = u + 2;
        float dr = sr[pp][u] - sr[pp][v], di = si[pp][u] - si[pp][v];
        sr[pp][u] += sr[pp][v];  si[pp][u] += si[pp][v];
        float er = dr * w4r - di * w4i;
        float ei = dr * w4i + di * w4r;
        sr[pp][v] = er * CA_[4 * k] + ei * SA_[4 * k];
        si[pp][v] = ei * CA_[4 * k] - er * SA_[4 * k];
    }
    // ---- stage h=64: pairs (u, u+1), tw = wL8 ----
    #pragma unroll
    for (int pp = 0; pp < 2; ++pp)
    #pragma unroll
    for (int u = 0; u < 16; u += 2) {
        const int v = u + 1;
        float dr = sr[pp][u] - sr[pp][v], di = si[pp][u] - si[pp][v];
        sr[pp][u] += sr[pp][v];  si[pp][u] += si[pp][v];
        sr[pp][v] = dr * w8r - di * w8i;
        si[pp][v] = dr * w8i + di * w8r;
    }

    // ---- cross-lane stages h=32..2 ----
#define SHFL_STAGE(H, PR, PI)                                       \
    {                                                               \
        const int hi_ = lane & (H);                                 \
        _Pragma("unroll")                                           \
        for (int pp = 0; pp < 2; ++pp)                              \
        _Pragma("unroll")                                           \
        for (int r = 0; r < 16; ++r) {                              \
            float orr = __shfl_xor(sr[pp][r], (H));                 \
            float oii = __shfl_xor(si[pp][r], (H));                 \
            float ddr = sr[pp][r] - orr, ddi = si[pp][r] - oii;     \
            float ssr = sr[pp][r] + orr, ssi = si[pp][r] + oii;     \
            sr[pp][r] = hi_ ? (ddr * (PR) - ddi * (PI)) : ssr;      \
            si[pp][r] = hi_ ? (ddr * (PI) + ddi * (PR)) : ssi;      \
        }                                                           \
    }
    SHFL_STAGE(32, w16r,  w16i)
    SHFL_STAGE(16, w32r,  w32i)
    SHFL_STAGE(8,  w64r,  w64i)
    SHFL_STAGE(4,  w128r, w128i)
    SHFL_STAGE(2,  w256r, w256i)
#undef SHFL_STAGE
    // ---- h=1: tw = (-1)^lane ----
    {
        const int hi_ = lane & 1;
        #pragma unroll
        for (int pp = 0; pp < 2; ++pp)
        #pragma unroll
        for (int r = 0; r < 16; ++r) {
            float orr = __shfl_xor(sr[pp][r], 1);
            float oii = __shfl_xor(si[pp][r], 1);
            sr[pp][r] = hi_ ? (orr - sr[pp][r]) : (sr[pp][r] + orr);
            si[pp][r] = hi_ ? (oii - si[pp][r]) : (si[pp][r] + oii);
        }
    }

    // ---- extract: value at (r,lane) is S[f], f = rev6(lane)*16 + rev4(r) ----
    const int m6 = (int)(__brev((unsigned)lane) >> 26);
    #pragma unroll
    for (int pp = 0; pp < 2; ++pp) {
        const int cb = 4 * wv + 2 * pp;
        if ((lane & 1) == 0) {
            const int fb = m6 << 4;
            #pragma unroll
            for (int r = 0; r < 16; ++r) {
                const int f = fb + R4_[r];
                ot[OTI(f) + cb]     = sr[pp][r];   // Re S = Re A[f]
                ot[OTI(f) + cb + 1] = si[pp][r];   // Im S = Re B[f]
            }
        } else if (lane == 1) {
            ot[OTI(512) + cb]     = sr[pp][0];     // f = 512
            ot[OTI(512) + cb + 1] = si[pp][0];
        }
    }

    __syncthreads();

    // ---- flush: 16 consecutive t per f row (64B segments) ----
    for (int it = 0; it < 33; ++it) {
        const int idx = tid + it * 256;
        if (idx < N_FREQ * FPB) {
            const int f = idx >> 4, c = idx & 15;
            const int t = t0 + c;
            if (t < N_FRAMES) {
                unsigned long long o =
                    (unsigned long long)(b * N_FREQ + f) * N_FRAMES
                    + (unsigned long long)t;
                if (o < cap) out[o] = ot[OTI(f) + c];
            }
        }
    }
}

extern "C" void kernel_launch(void* const* d_in, const int* in_sizes, int n_in,
                              void* d_out, int out_size, void* d_ws, size_t ws_size,
                              hipStream_t stream)
{
    const float* x = (const float*)d_in[0];
    float* out = (float*)d_out;
    if (!x || !out || out_size <= 0) return;

    unsigned long long cap = (unsigned long long)(long long)out_size;

    dim3 grid(BATCH * NTILES);   // 1040 blocks
    dim3 block(256);
    stft_kernel<<<grid, block, 0, stream>>>(x, out, cap);
}